// Round 1
// baseline (501.705 us; speedup 1.0000x reference)
//
#include <hip/hip_runtime.h>
#include <hip/hip_bf16.h>
#include <math.h>

// ---------------- constants ----------------
#define BATCH   16
#define TFRM    4096          // frames per batch (= L)
#define DIM     512
#define ODIM    1026
#define KP      513           // ODIM/2
#define NFFT    1024
#define HOP     256
#define WINL    1024
#define PADC    384           // (WIN-HOP)/2
#define MROWS   (BATCH*TFRM)  // 65536
#define NPAD    1152          // ODIM padded to multiple of 128 (GEMM-friendly)
#define OUTLEN  1048576       // per-batch output samples
#define ENVLEN  1049344       // (T-1)*HOP + WIN
#define TWO_PI_OVER_N 0.006135923151542565f  // 2*pi/1024

typedef __bf16 bf16x8 __attribute__((ext_vector_type(8)));
typedef float  f32x4  __attribute__((ext_vector_type(4)));

__device__ __forceinline__ ushort f2bf(float f) {
  union { float f; unsigned u; } v; v.f = f;
  unsigned u = v.u;
  unsigned r = (u + 0x7FFFu + ((u >> 16) & 1u)) >> 16;
  return (ushort)r;
}
__device__ __forceinline__ float bf2f(ushort h) {
  union { unsigned u; float f; } v; v.u = ((unsigned)h) << 16;
  return v.f;
}

// ---------------- prep: x fp32 -> bf16 ----------------
__global__ void k_prep_x(const float4* __restrict__ x, ushort4* __restrict__ o, int n4) {
  int i = blockIdx.x * blockDim.x + threadIdx.x;
  int stride = gridDim.x * blockDim.x;
  for (; i < n4; i += stride) {
    float4 v = x[i];
    ushort4 r;
    r.x = f2bf(v.x); r.y = f2bf(v.y); r.z = f2bf(v.z); r.w = f2bf(v.w);
    o[i] = r;
  }
}

// ---------------- prep: W fp32 [1026][512] -> bf16 padded [1152][512] ----------------
__global__ void k_prep_w(const float* __restrict__ W, ushort* __restrict__ o) {
  int i = blockIdx.x * 256 + threadIdx.x;          // over 1152*512
  if (i >= NPAD * DIM) return;
  int r = i >> 9;                                  // row (DIM=512)
  o[i] = (r < ODIM) ? f2bf(W[i]) : (ushort)0;
}

// ---------------- basis: BasisT[n][j] bf16, n in [0,1024), j in [0,1152) ----------------
// frames[n] = win[n]/1024 * ( a0 + a512*(-1)^n + 2*sum_{k=1}^{511} (a_k cos - b_k sin) )
__global__ void k_basis(ushort* __restrict__ bas) {
  int n = blockIdx.x;
  float wn = 0.5f - 0.5f * cosf((float)n * TWO_PI_OVER_N);
  float sc = wn * (1.0f / 1024.0f);
  for (int j = threadIdx.x; j < NPAD; j += 256) {
    float v = 0.0f;
    if (j < KP) {
      int k = j;
      int r = (k * n) & 1023;                      // exact integer phase reduction
      float c = cosf((float)r * TWO_PI_OVER_N);
      v = ((k == 0 || k == 512) ? 1.0f : 2.0f) * c;
    } else if (j < ODIM) {
      int k = j - KP;
      if (k != 0 && k != 512) {
        int r = (k * n) & 1023;
        v = -2.0f * sinf((float)r * TWO_PI_OVER_N);
      }
    }
    bas[n * NPAD + j] = f2bf(v * sc);
  }
}

// ---------------- envelope: inv_env[s] = 1 / sum_t win^2[s-256t] ----------------
__global__ void k_env(float* __restrict__ inv_env) {
  int s = blockIdx.x * 256 + threadIdx.x;
  if (s >= ENVLEN) return;
  float e = 0.0f;
  int t0 = s >> 8;
#pragma unroll
  for (int q = 0; q < 4; ++q) {
    int t = t0 - q;
    if (t >= 0 && t < TFRM) {
      int n = (s & 255) + (q << 8);
      float w = 0.5f - 0.5f * cosf((float)n * TWO_PI_OVER_N);
      e += w * w;
    }
  }
  inv_env[s] = 1.0f / e;   // inf only in the cropped-away edge region (never read)
}

// ---------------- pointwise: h -> (mag*cos, mag*sin), in place, bf16 ----------------
__global__ void k_act(ushort* __restrict__ h, const float* __restrict__ bias) {
  int f = blockIdx.x;
  ushort* row = h + (size_t)f * NPAD;
  for (int k = threadIdx.x; k < KP; k += 256) {
    float hm = bf2f(row[k]) + bias[k];
    float hp = bf2f(row[KP + k]) + bias[KP + k];
    float mag = fminf(expf(hm), 100.0f);
    float s, c;
    sincosf(hp, &s, &c);
    row[k]      = f2bf(mag * c);
    row[KP + k] = f2bf(mag * s);
  }
  for (int j = ODIM + threadIdx.x; j < NPAD; j += 256) row[j] = 0;  // keep pad zero
}

// ---------------- GEMM (B^T form): C[m][n] = sum_k A[m][k] * Bt[n][k], bf16 in/out, fp32 acc
// 128x128 tile, BK=32, 4 waves (2x2 of 64x64), double-buffered LDS via global_load_lds w16
__global__ __launch_bounds__(256) void k_gemm(const ushort* __restrict__ A, int lda,
                                              const ushort* __restrict__ Bt, int ldb,
                                              ushort* __restrict__ C, int ldc,
                                              int nbn, int K) {
  __shared__ __align__(16) ushort lds[2][2][128 * 32];
  const int tid  = threadIdx.x;
  const int bid  = blockIdx.x;
  const int bm   = bid / nbn;
  const int bn   = bid - bm * nbn;
  const int lane = tid & 63;
  const int wv   = tid >> 6;
  const int wr   = (wv >> 1) * 64;
  const int wc   = (wv & 1) * 64;
  const int lr   = lane & 15;
  const int lk   = (lane >> 4) << 3;

  f32x4 acc[4][4] = {};

  auto stage = [&](const ushort* __restrict__ g, int ld, int row0, int k0, ushort* l) {
#pragma unroll
    for (int p = 0; p < 2; ++p) {
      int i = tid + p * 256;
      const ushort* gp = g + (size_t)(row0 + (i >> 2)) * ld + k0 + ((i & 3) << 3);
      ushort* lp = l + ((i >> 6) << 9);   // wave-uniform LDS base; HW scatters lane*16B
      __builtin_amdgcn_global_load_lds(
          (const __attribute__((address_space(1))) void*)gp,
          (__attribute__((address_space(3))) void*)lp, 16, 0, 0);
    }
  };

  const int NT = K >> 5;
  stage(A,  lda, bm * 128, 0, &lds[0][0][0]);
  stage(Bt, ldb, bn * 128, 0, &lds[0][1][0]);
  asm volatile("s_waitcnt vmcnt(0)" ::: "memory");
  __syncthreads();

  for (int t = 0; t < NT; ++t) {
    const int cur = t & 1;
    if (t + 1 < NT) {
      stage(A,  lda, bm * 128, (t + 1) << 5, &lds[cur ^ 1][0][0]);
      stage(Bt, ldb, bn * 128, (t + 1) << 5, &lds[cur ^ 1][1][0]);
    }
    const ushort* lA = &lds[cur][0][0];
    const ushort* lB = &lds[cur][1][0];
    bf16x8 aF[4], bF[4];
#pragma unroll
    for (int m = 0; m < 4; ++m)
      aF[m] = *(const bf16x8*)(lA + (wr + m * 16 + lr) * 32 + lk);
#pragma unroll
    for (int n = 0; n < 4; ++n)
      bF[n] = *(const bf16x8*)(lB + (wc + n * 16 + lr) * 32 + lk);
#pragma unroll
    for (int m = 0; m < 4; ++m)
#pragma unroll
      for (int n = 0; n < 4; ++n)
        acc[m][n] = __builtin_amdgcn_mfma_f32_16x16x32_bf16(aF[m], bF[n], acc[m][n], 0, 0, 0);
    asm volatile("s_waitcnt vmcnt(0)" ::: "memory");
    __syncthreads();
  }

  const int r0 = bm * 128 + wr + ((lane >> 4) << 2);
  const int c0 = bn * 128 + wc + lr;
#pragma unroll
  for (int m = 0; m < 4; ++m)
#pragma unroll
    for (int j = 0; j < 4; ++j) {
      size_t rowoff = (size_t)(r0 + m * 16 + j) * ldc + c0;
#pragma unroll
      for (int n = 0; n < 4; ++n)
        C[rowoff + n * 16] = f2bf(acc[m][n][j]);
    }
}

// ---------------- overlap-add + env division + crop ----------------
__global__ void k_oa(const ushort* __restrict__ frames, const float* __restrict__ inv_env,
                     float* __restrict__ out) {
  int u = blockIdx.x * 256 + threadIdx.x;   // 16 * 1048576 threads exactly
  int b  = u >> 20;
  int sp = u & (OUTLEN - 1);
  int s  = sp + PADC;
  int t0 = s >> 8;
  float acc = 0.0f;
#pragma unroll
  for (int q = 0; q < 4; ++q) {
    int t = t0 - q;
    if (t >= 0 && t < TFRM) {
      int n = (s & 255) + (q << 8);
      acc += bf2f(frames[(((size_t)(b << 12) + t) << 10) + n]);
    }
  }
  out[u] = acc * inv_env[s];
}

// ---------------- launch ----------------
extern "C" void kernel_launch(void* const* d_in, const int* in_sizes, int n_in,
                              void* d_out, int out_size, void* d_ws, size_t ws_size,
                              hipStream_t stream) {
  const float* x    = (const float*)d_in[0];
  const float* W    = (const float*)d_in[1];
  const float* bias = (const float*)d_in[2];
  float* out = (float*)d_out;
  char* ws = (char*)d_ws;

  // ws layout (bytes, all 256-aligned):
  //   [0, 134217728)            x_bf16 (67MB, dead after GEMM1)  ALIASED WITH frames (134MB)
  //   [134217728, 135397376)    Wp bf16 [1152][512]
  //   [135397376, 137756672)    BasisT bf16 [1024][1152]
  //   [137756672, 141954048)    inv_env fp32 [1049344]
  //   [141954048, 292948992)    h / A2 bf16 [65536][1152]
  ushort* xbf    = (ushort*)(ws + 0);
  ushort* frames = (ushort*)(ws + 0);
  ushort* Wp     = (ushort*)(ws + 134217728);
  ushort* bas    = (ushort*)(ws + 135397376);
  float*  ienv   = (float*) (ws + 137756672);
  ushort* h      = (ushort*)(ws + 141954048);

  k_prep_x<<<8192, 256, 0, stream>>>((const float4*)x, (ushort4*)xbf, (BATCH * TFRM * DIM) / 4);
  k_prep_w<<<(NPAD * DIM) / 256, 256, 0, stream>>>(W, Wp);
  k_basis<<<NFFT, 256, 0, stream>>>(bas);
  k_env<<<(ENVLEN + 255) / 256, 256, 0, stream>>>(ienv);

  // GEMM1: h[65536][1152] = xbf[65536][512] . Wp[1152][512]^T
  k_gemm<<<(MROWS / 128) * (NPAD / 128), 256, 0, stream>>>(xbf, DIM, Wp, DIM, h, NPAD, NPAD / 128, DIM);

  // pointwise nonlinearity in place
  k_act<<<MROWS, 256, 0, stream>>>(h, bias);

  // GEMM2: frames[65536][1024] = h[65536][1152] . BasisT[1024][1152]^T
  k_gemm<<<(MROWS / 128) * (NFFT / 128), 256, 0, stream>>>(h, NPAD, bas, NPAD, frames, NFFT, NFFT / 128, NPAD);

  // overlap-add, envelope normalize, crop
  k_oa<<<(BATCH * OUTLEN) / 256, 256, 0, stream>>>(frames, ienv, out);
}